// Round 4
// baseline (370.620 us; speedup 1.0000x reference)
//
#include <hip/hip_runtime.h>
#include <hip/hip_bf16.h>

using bf16 = __hip_bfloat16;
typedef __attribute__((ext_vector_type(8))) short bf16x8;
typedef __attribute__((ext_vector_type(4))) short bf16x4;
typedef __attribute__((ext_vector_type(4))) float f32x4;

static constexpr int TB  = 4;
static constexpr int TS  = 1024;
static constexpr int TD  = 1024;
static constexpr int TNH = 16;
static constexpr int TDH = 64;
static constexpr int TDI = 4096;

__device__ __forceinline__ void gll16(const bf16* g, bf16* l)
{
    __builtin_amdgcn_global_load_lds(
        (const __attribute__((address_space(1))) void*)g,
        (__attribute__((address_space(3))) void*)l, 16, 0, 0);
}

// ---------------- fallback ----------------
__global__ __launch_bounds__(256) void zero_out_k(float* __restrict__ out, long n)
{
    long i = (long)blockIdx.x * 256 + threadIdx.x;
    if (i < n) out[i] = 0.0f;
}

// ---------------- fp32 -> bf16, 8/thread, two tensors ----------------
__global__ __launch_bounds__(256) void convert2_f2b(const float* __restrict__ a,
                                                    const float* __restrict__ b,
                                                    bf16* __restrict__ oa,
                                                    bf16* __restrict__ ob, long n)
{
    const float* src = blockIdx.y ? b : a;
    bf16* dst = blockIdx.y ? ob : oa;
    long i = ((long)blockIdx.x * 256 + threadIdx.x) * 8;
    if (i >= n) return;
    float4 f0 = *(const float4*)(src + i);
    float4 f1 = *(const float4*)(src + i + 4);
    bf16 t[8] = {__float2bfloat16(f0.x), __float2bfloat16(f0.y),
                 __float2bfloat16(f0.z), __float2bfloat16(f0.w),
                 __float2bfloat16(f1.x), __float2bfloat16(f1.y),
                 __float2bfloat16(f1.z), __float2bfloat16(f1.w)};
    *(bf16x8*)(dst + i) = *(bf16x8*)t;
}

// ---------------- transpose fp32 [R,C] -> bf16 [C,R] ----------------
__global__ __launch_bounds__(256) void transpose_f2b(const float* __restrict__ in,
                                                     bf16* __restrict__ out,
                                                     int R, int C)
{
    __shared__ float tile[32][33];
    int c0 = blockIdx.x * 32, r0 = blockIdx.y * 32;
    int tx = threadIdx.x & 31, ty = threadIdx.x >> 5;
#pragma unroll
    for (int dy = 0; dy < 32; dy += 8)
        tile[ty + dy][tx] = in[(long)(r0 + ty + dy) * C + (c0 + tx)];
    __syncthreads();
#pragma unroll
    for (int dy = 0; dy < 32; dy += 8)
        out[(long)(c0 + ty + dy) * R + (r0 + tx)] = __float2bfloat16(tile[tx][ty + dy]);
}

// ---------------- 5x square D x D transpose ----------------
__global__ __launch_bounds__(256) void transpose5_f2b(const float* __restrict__ p0,
                                                      const float* __restrict__ p1,
                                                      const float* __restrict__ p2,
                                                      const float* __restrict__ p3,
                                                      const float* __restrict__ p4,
                                                      bf16* __restrict__ dstBase)
{
    __shared__ float tile[32][33];
    const int D = TD;
    int z = blockIdx.z;
    const float* in = (z == 0) ? p0 : (z == 1) ? p1 : (z == 2) ? p2 : (z == 3) ? p3 : p4;
    bf16* out = dstBase + (long)z * D * D;
    int c0 = blockIdx.x * 32, r0 = blockIdx.y * 32;
    int tx = threadIdx.x & 31, ty = threadIdx.x >> 5;
#pragma unroll
    for (int dy = 0; dy < 32; dy += 8)
        tile[ty + dy][tx] = in[(long)(r0 + ty + dy) * D + (c0 + tx)];
    __syncthreads();
#pragma unroll
    for (int dy = 0; dy < 32; dy += 8)
        out[(long)(c0 + ty + dy) * D + (r0 + tx)] = __float2bfloat16(tile[tx][ty + dy]);
}

// ======================================================================
// 256x256 x BK=64, 8-wave (2Mx4N), 8-phase pipelined GEMM (T1..T5)
// MODE 1: fused QKV+R, fragment-packed writes for Q/K/R AND V.
// MODE 2: bias+relu bf16.
// Supertile mapping: each XCD owns 4x4-tile rectangles (L2 working set
// ~4MB vs 8MB+ column strips).
// ======================================================================

__device__ __forceinline__ void stage_half(const bf16* __restrict__ X, long ldx,
                                           long rbase, long kcol,
                                           bf16* lds, int srow)
{
    gll16(X + (rbase + srow) * ldx + kcol, lds);
    gll16(X + (rbase + 128 + srow) * ldx + kcol, lds + 4096);
}

template<int MODE>
__global__ __launch_bounds__(512, 2) void gemm256_k(
    const bf16* __restrict__ A, long lda,
    const bf16* __restrict__ Bt, long ldb,
    bf16* __restrict__ O0, bf16* __restrict__ O1,
    bf16* __restrict__ O2, bf16* __restrict__ O3,
    const float* __restrict__ bias,
    int K, int GY, long ldc)
{
    __shared__ bf16 LDSbf[65536];   // 128 KiB

    const int NT = K >> 6;
    const int NI = NT >> 1;

    // bijective XCD swizzle: each XCD = contiguous wgid chunk of 32
    const int nwg = gridDim.x;
    const int orig = blockIdx.x;
    const int q = nwg >> 3, r = nwg & 7;
    const int xcd = orig & 7, idx = orig >> 3;
    const int wgid = (xcd < r ? xcd * (q + 1) : r * (q + 1) + (xcd - r) * q) + idx;

    // supertile mapping: 16 supertiles of 4x4 tiles
    int tx, ty;
    {
        const int l = wgid & 15;
        const int st = wgid >> 4;
        const int lty = l & 3, ltx = l >> 2;
        if (MODE == 1) {
            if (st < 12) { ty = (st & 3) * 4 + lty; tx = (st >> 2) * 4 + ltx; }
            else { int s2 = st - 12; ty = 16 + s2 * 4 + lty; tx = 12 + ltx; }
        } else {
            ty = (st & 3) * 4 + lty; tx = (st >> 2) * 4 + ltx;
        }
    }
    const long row0 = (long)ty * 256;
    const int col0 = tx * 256;

    const int tid = threadIdx.x;
    const int lane = tid & 63;
    const int wave = tid >> 6;       // 0..7
    const int wm2 = wave >> 2;       // 0..1  (M half)
    const int wn4 = wave & 3;        // 0..3  (N quarter)
    const int l15 = lane & 15;
    const int lq  = lane >> 4;       // 0..3

    const int slot = ((l15 & 1) << 2) | (lq ^ ((l15 >> 1) & 3));
    const int rdA = (wm2 * 64 + (l15 >> 1)) * 64 + slot * 8;
    const int rdB = 16384 + (wn4 * 32 + (l15 >> 1)) * 64 + slot * 8;

    const int srow  = wave * 16 + ((lane >> 3) << 1) + ((lane >> 2) & 1);
    const int scol8 = ((lane & 3) ^ ((lane >> 3) & 3)) * 8;

    f32x4 acc[8][4] = {};
    bf16x8 af[8], bb[4];

#define SA(t, db, kh) stage_half(A, lda, row0, (long)(t) * 64 + (kh) * 32 + scol8, \
                                 LDSbf + (db) * 32768 + (kh) * 8192 + wave * 512, srow)
#define SB(t, db, kh) stage_half(Bt, ldb, (long)col0, (long)(t) * 64 + (kh) * 32 + scol8, \
                                 LDSbf + (db) * 32768 + 16384 + (kh) * 8192 + wave * 512, srow)
#define RD_A(bp, kh) do {                                                              \
    _Pragma("unroll")                                                                  \
    for (int i_ = 0; i_ < 8; ++i_)                                                     \
        af[i_] = *(const bf16x8*)(LDSbf + (bp) * 32768 + (kh) * 8192 + rdA + i_ * 512);\
    } while (0)
#define RD_B(bp, kh, jh) do {                                                          \
    bb[(jh)*2]   = *(const bf16x8*)(LDSbf + (bp)*32768 + (kh)*8192 + rdB + ((jh)*2)*512);   \
    bb[(jh)*2+1] = *(const bf16x8*)(LDSbf + (bp)*32768 + (kh)*8192 + rdB + ((jh)*2+1)*512); \
    } while (0)
#define MM(jh) do {                                                                    \
    __builtin_amdgcn_s_setprio(1);                                                     \
    _Pragma("unroll")                                                                  \
    for (int i_ = 0; i_ < 8; ++i_) {                                                   \
        acc[i_][(jh)*2]   = __builtin_amdgcn_mfma_f32_16x16x32_bf16(af[i_], bb[(jh)*2],   acc[i_][(jh)*2],   0, 0, 0); \
        acc[i_][(jh)*2+1] = __builtin_amdgcn_mfma_f32_16x16x32_bf16(af[i_], bb[(jh)*2+1], acc[i_][(jh)*2+1], 0, 0, 0); \
    }                                                                                  \
    __builtin_amdgcn_s_setprio(0);                                                     \
    } while (0)
#define BAR       __builtin_amdgcn_s_barrier()
#define WLGKM0    do { asm volatile("s_waitcnt lgkmcnt(0)" ::: "memory");              \
                       __builtin_amdgcn_sched_barrier(0); } while (0)
#define WVM6      asm volatile("s_waitcnt vmcnt(6)" ::: "memory")

    SA(0, 0, 0); SB(0, 0, 0); SA(0, 0, 1); SB(0, 0, 1); SA(1, 1, 0);
    WVM6; BAR;

    for (int it = 0; it < NI; ++it) {
        const int T  = 2 * it;
        const int t1 = T + 1;
        const int t2 = (T + 2 < NT) ? T + 2 : NT - 1;
        const int t3 = (T + 3 < NT) ? T + 3 : NT - 1;

        RD_A(0, 0); RD_B(0, 0, 0); SB(t1, 1, 0);
        BAR; WLGKM0; MM(0); BAR;
        RD_B(0, 0, 1); SA(t1, 1, 1);
        BAR; WLGKM0; MM(1); WVM6; BAR;
        RD_A(0, 1); RD_B(0, 1, 0); SB(t1, 1, 1);
        BAR; WLGKM0; MM(0); BAR;
        RD_B(0, 1, 1); SA(t2, 0, 0);
        BAR; WLGKM0; MM(1); WVM6; BAR;
        RD_A(1, 0); RD_B(1, 0, 0); SB(t2, 0, 0);
        BAR; WLGKM0; MM(0); BAR;
        RD_B(1, 0, 1); SA(t2, 0, 1);
        BAR; WLGKM0; MM(1); WVM6; BAR;
        RD_A(1, 1); RD_B(1, 1, 0); SB(t2, 0, 1);
        BAR; WLGKM0; MM(0); BAR;
        RD_B(1, 1, 1); SA(t3, 1, 0);
        BAR; WLGKM0; MM(1); WVM6; BAR;
    }
    asm volatile("s_waitcnt vmcnt(0)" ::: "memory");

#undef SA
#undef SB
#undef RD_A
#undef RD_B
#undef MM
#undef BAR
#undef WLGKM0
#undef WVM6

    // ---- epilogue ----
    if (MODE == 1) {
        const int sel = tx >> 2;                       // 0=Q 1=K 2=V 3=R
        bf16* O = (sel == 0) ? O0 : (sel == 1) ? O1 : (sel == 2) ? O2 : O3;
        const int coladj = sel << 10;
        const long rowadj = (sel == 3) ? 4096 : 0;
#pragma unroll
        for (int i = 0; i < 8; ++i) {
            long mrow0 = row0 - rowadj + wm2 * 128 + i * 16 + lq * 4;
#pragma unroll
            for (int j = 0; j < 4; ++j) {
                int nc = col0 - coladj + wn4 * 64 + j * 16 + l15;
                if (sel == 2) {
                    // V packed: 4 consecutive s -> one 8B store
                    long b_ = mrow0 >> 10;
                    int s  = (int)mrow0 & 1023;
                    int n_ = nc >> 6, d = nc & 63;
                    long pidx = ((b_ * 16 + n_) << 16)
                              + ((d >> 4) * 128 + (s >> 3)) * 128
                              + (d & 15) * 8 + (s & 7);
                    bf16 t4[4];
#pragma unroll
                    for (int rg = 0; rg < 4; ++rg)
                        t4[rg] = __float2bfloat16(acc[i][j][rg]);
                    *(bf16x4*)(O + pidx) = *(bf16x4*)t4;
                } else {
#pragma unroll
                    for (int rg = 0; rg < 4; ++rg) {
                        float v = acc[i][j][rg];
                        if (sel == 0) v += bias[nc];
                        long mrow = mrow0 + rg;
                        long b_ = mrow >> 10;
                        int s  = (int)mrow & 1023;
                        int n_ = nc >> 6, d = nc & 63;
                        long pidx = ((b_ * 16 + n_) << 16)
                                  + ((s >> 4) * 8 + (d >> 3)) * 128
                                  + (s & 15) * 8 + (d & 7);
                        O[pidx] = __float2bfloat16(v);
                    }
                }
            }
        }
    } else {
#pragma unroll
        for (int i = 0; i < 8; ++i) {
            long rb = (row0 + wm2 * 128 + i * 16 + lq * 4) * ldc;
#pragma unroll
            for (int j = 0; j < 4; ++j) {
                int nc = col0 + wn4 * 64 + j * 16 + l15;
#pragma unroll
                for (int rg = 0; rg < 4; ++rg) {
                    float v = acc[i][j][rg] + bias[nc];
                    v = fmaxf(v, 0.0f);
                    O0[rb + (long)rg * ldc + nc] = __float2bfloat16(v);
                }
            }
        }
    }
}

// ======================================================================
// 128x128 x BK=64, 8-wave (2Mx4N), 4-phase pipelined GEMM, no split-K.
// LDS 64KB -> 2 blocks/CU. Supertile mapping 8x4 per XCD.
// MODE 3: z = acc + residf(fp32)           -> Zf fp32   (Wo + w residual)
// MODE 4: z = acc + bias + residb(bf16)    -> Zf fp32   (FFN2 + b2 + x)
// ======================================================================
template<int MODE>
__global__ __launch_bounds__(512, 2) void gemm128_k(
    const bf16* __restrict__ A, long lda,
    const bf16* __restrict__ Bt, long ldb,
    float* __restrict__ Zf,
    const float* __restrict__ residf, const bf16* __restrict__ residb,
    const float* __restrict__ bias,
    int K, int GY, long ldc)
{
    __shared__ bf16 LDSbf[32768];   // 64 KiB

    const int NT = K >> 6;
    const int NI = NT >> 1;

    const int nwg = gridDim.x;
    const int orig = blockIdx.x;
    const int q = nwg >> 3, r = nwg & 7;
    const int xcd = orig & 7, idx = orig >> 3;
    const int wgid = (xcd < r ? xcd * (q + 1) : r * (q + 1) + (xcd - r) * q) + idx;

    // supertile: 8 supertiles of 8ty x 4tx (grid 32x8)
    const int l = wgid & 31;
    const int sup = wgid >> 5;
    const int ty = (sup & 3) * 8 + (l & 7);
    const int tx = (sup >> 2) * 4 + (l >> 3);
    const long row0 = (long)ty * 128;
    const long col0 = (long)tx * 128;

    const int tid = threadIdx.x;
    const int lane = tid & 63;
    const int wave = tid >> 6;
    const int wm2 = wave >> 2;       // 0..1: 64-row half
    const int wn4 = wave & 3;        // 0..3: 32-col quarter
    const int l15 = lane & 15;
    const int lq  = lane >> 4;

    const int slot = ((l15 & 1) << 2) | (lq ^ ((l15 >> 1) & 3));
    const int rdA = (wm2 * 32 + (l15 >> 1)) * 64 + slot * 8;
    const int rdB = 8192 + (wn4 * 16 + (l15 >> 1)) * 64 + slot * 8;

    const int srow  = (tid >> 3) * 2 + ((tid >> 2) & 1);          // 0..127
    const int scol8 = ((tid & 3) ^ ((tid >> 3) & 3)) * 8;

    f32x4 acc[4][2] = {};
    bf16x8 af[4], bb[2];

#define SA(t, db, kh) gll16(A + (row0 + srow) * lda + (long)(t) * 64 + (kh) * 32 + scol8, \
                            LDSbf + (db) * 16384 + (kh) * 4096 + wave * 512)
#define SB(t, db, kh) gll16(Bt + (col0 + srow) * ldb + (long)(t) * 64 + (kh) * 32 + scol8, \
                            LDSbf + (db) * 16384 + 8192 + (kh) * 4096 + wave * 512)
#define RD(db, kh) do {                                                                \
    _Pragma("unroll")                                                                  \
    for (int i_ = 0; i_ < 4; ++i_)                                                     \
        af[i_] = *(const bf16x8*)(LDSbf + (db) * 16384 + (kh) * 4096 + rdA + i_ * 512);\
    _Pragma("unroll")                                                                  \
    for (int j_ = 0; j_ < 2; ++j_)                                                     \
        bb[j_] = *(const bf16x8*)(LDSbf + (db) * 16384 + (kh) * 4096 + rdB + j_ * 512);\
    } while (0)
#define MM8 do {                                                                       \
    __builtin_amdgcn_s_setprio(1);                                                     \
    _Pragma("unroll")                                                                  \
    for (int i_ = 0; i_ < 4; ++i_) {                                                   \
        acc[i_][0] = __builtin_amdgcn_mfma_f32_16x16x32_bf16(af[i_], bb[0], acc[i_][0], 0, 0, 0); \
        acc[i_][1] = __builtin_amdgcn_mfma_f32_16x16x32_bf16(af[i_], bb[1], acc[i_][1], 0, 0, 0); \
    }                                                                                  \
    __builtin_amdgcn_s_setprio(0);                                                     \
    } while (0)
#define BAR       __builtin_amdgcn_s_barrier()
#define WLGKM0    do { asm volatile("s_waitcnt lgkmcnt(0)" ::: "memory");              \
                       __builtin_amdgcn_sched_barrier(0); } while (0)
#define WVM4      asm volatile("s_waitcnt vmcnt(4)" ::: "memory")

    SA(0, 0, 0); SB(0, 0, 0); SA(0, 0, 1); SB(0, 0, 1); SA(1, 1, 0); SB(1, 1, 0);
    WVM4; BAR;

    for (int it = 0; it < NI; ++it) {
        const int T  = 2 * it;
        const int t1 = T + 1;
        const int t2 = (T + 2 < NT) ? T + 2 : NT - 1;
        const int t3 = (T + 3 < NT) ? T + 3 : NT - 1;

        RD(0, 0); SA(t1, 1, 1); SB(t1, 1, 1);
        BAR; WLGKM0; MM8; WVM4; BAR;
        RD(0, 1); SA(t2, 0, 0); SB(t2, 0, 0);
        BAR; WLGKM0; MM8; WVM4; BAR;
        RD(1, 0); SA(t2, 0, 1); SB(t2, 0, 1);
        BAR; WLGKM0; MM8; WVM4; BAR;
        RD(1, 1); SA(t3, 1, 0); SB(t3, 1, 0);
        BAR; WLGKM0; MM8; WVM4; BAR;
    }
    asm volatile("s_waitcnt vmcnt(0)" ::: "memory");

#undef SA
#undef SB
#undef RD
#undef MM8
#undef BAR
#undef WLGKM0
#undef WVM4

    // ---- fused epilogue -> fp32 Z ----
#pragma unroll
    for (int i = 0; i < 4; ++i) {
        long mrow0 = row0 + wm2 * 64 + i * 16 + lq * 4;
#pragma unroll
        for (int j = 0; j < 2; ++j) {
            int nc = (int)col0 + wn4 * 32 + j * 16 + l15;
#pragma unroll
            for (int rg = 0; rg < 4; ++rg) {
                long ridx = (mrow0 + rg) * ldc + nc;
                float v = acc[i][j][rg];
                if (MODE == 3) v += residf[ridx];
                else           v += bias[nc] + __bfloat162float(residb[ridx]);
                Zf[ridx] = v;
            }
        }
    }
}

// ======================================================================
// fused flash attention with Transformer-XL rel-shift — single-wave
// blocks, 16 q-rows per wave, fragment-packed direct global loads.
// grid = 4096 x 64 threads -> 4 waves/SIMD. LDS 5.2KB/block.
// setprio(1) around MFMA clusters (T5, m191-positive regime).
// ======================================================================
__global__ __launch_bounds__(64, 4) void flash_attn(
    const bf16* __restrict__ Qpk, const bf16* __restrict__ Kpk,
    const bf16* __restrict__ RRpk, const bf16* __restrict__ Vpk,
    const float* __restrict__ wbias, const float* __restrict__ rbias,
    bf16* __restrict__ Oa)
{
    const int S = TS, D = TD;
    __shared__ bf16 scr[16 * 161];   // 5152 B

    const int orig = blockIdx.x;               // 0..4095
    const int xcd = orig & 7, idx = orig >> 3; // idx 0..511
    const int bn = xcd * 8 + (idx & 7);        // 8 bn per XCD
    const int rem = idx >> 3;                  // 0..63
    const int r16 = 63 - rem;                  // heavy row-groups first
    const int it = r16 >> 3;
    const int rowstart = r16 * 16;
    const int dwq = (r16 & 7) * 16;
    const int b = bn >> 4, n = bn & 15;

    const int lane = threadIdx.x;
    const int l15 = lane & 15, lq = lane >> 4;

    const bf16* Qb = Qpk  + (long)bn * 65536;
    const bf16* Kb = Kpk  + (long)bn * 65536;
    const bf16* Rb = RRpk + (long)bn * 65536;
    const bf16* Vb = Vpk  + (long)bn * 65536;

    bf16x8 afw[2], afr[2];
#pragma unroll
    for (int ks = 0; ks < 2; ++ks) {
        afw[ks] = *(const bf16x8*)(Qb + (r16 * 8 + ks * 4 + lq) * 128 + l15 * 8);
        bf16 tmp[8];
#pragma unroll
        for (int jj = 0; jj < 8; ++jj) {
            int di_ = n * 64 + ks * 32 + lq * 8 + jj;
            float f = __bfloat162float(((const bf16*)&afw[ks])[jj])
                      + rbias[di_] - wbias[di_];
            tmp[jj] = __float2bfloat16(f);
        }
        afr[ks] = *(bf16x8*)tmp;
    }

    float mst[4], lst[4];
    f32x4 Oacc[4] = {};
#pragma unroll
    for (int rg = 0; rg < 4; ++rg) { mst[rg] = -1e30f; lst[rg] = 0.0f; }

    const int cofs16 = 1008 - rowstart;

    for (int jt = 0; jt <= it; ++jt) {
        const int j0 = jt * 128;
        const int rbt = (j0 + cofs16) >> 4;

        // ---- bd = (q + r_bias) . RR : 9 frags (144 cols), groups 5+4 ----
#pragma unroll
        for (int g = 0; g < 2; ++g) {
            const int NF = g ? 4 : 5;
            f32x4 bdl[5] = {};
#pragma unroll
            for (int ks = 0; ks < 2; ++ks) {
                bf16x8 bfr[5];
#pragma unroll
                for (int f = 0; f < 5; ++f) {
                    if (f < NF) {
                        int t = rbt + g * 5 + f;
                        if (t > 63) t = 63;   // clamped rows land only in masked cols
                        bfr[f] = *(const bf16x8*)(Rb + (t * 8 + ks * 4 + lq) * 128 + l15 * 8);
                    }
                }
                __builtin_amdgcn_s_setprio(1);
#pragma unroll
                for (int f = 0; f < 5; ++f)
                    if (f < NF)
                        bdl[f] = __builtin_amdgcn_mfma_f32_16x16x32_bf16(
                            afr[ks], bfr[f], bdl[f], 0, 0, 0);
                __builtin_amdgcn_s_setprio(0);
            }
#pragma unroll
            for (int f = 0; f < 5; ++f)
                if (f < NF)
#pragma unroll
                    for (int rg = 0; rg < 4; ++rg) {
                        int ldi = lq * 4 + rg;
                        scr[ldi * 161 + (g * 5 + f) * 16 + l15] =
                            __float2bfloat16(bdl[f][rg]);
                    }
        }

        // ---- ac = (q + w_bias) . K ----
        f32x4 ac[8] = {};
#pragma unroll
        for (int ks = 0; ks < 2; ++ks) {
            bf16x8 bk[8];
#pragma unroll
            for (int f = 0; f < 8; ++f)
                bk[f] = *(const bf16x8*)(
                    Kb + (((j0 >> 4) + f) * 8 + ks * 4 + lq) * 128 + l15 * 8);
            __builtin_amdgcn_s_setprio(1);
#pragma unroll
            for (int f = 0; f < 8; ++f)
                ac[f] = __builtin_amdgcn_mfma_f32_16x16x32_bf16(
                    afw[ks], bk[f], ac[f], 0, 0, 0);
            __builtin_amdgcn_s_setprio(0);
        }

        // ---- rel-shift add + scale + causal mask ----
        const bool diag = (jt == it);
#pragma unroll
        for (int nf = 0; nf < 8; ++nf)
#pragma unroll
            for (int rg = 0; rg < 4; ++rg) {
                int ldi = lq * 4 + rg;
                int col = nf * 16 + l15;
                float bdv = __bfloat162float(scr[ldi * 161 + (col + 15 - ldi)]);
                float s = (ac[nf][rg] + bdv) * 0.125f;
                if (diag && (col > dwq + ldi)) s = -1e30f;
                ac[nf][rg] = s;
            }

        // ---- online softmax ----
        float alpha[4];
#pragma unroll
        for (int rg = 0; rg < 4; ++rg) {
            float v = -1e30f;
#pragma unroll
            for (int nf = 0; nf < 8; ++nf) v = fmaxf(v, ac[nf][rg]);
            for (int o = 8; o; o >>= 1) v = fmaxf(v, __shfl_xor(v, o));
            float mn = fmaxf(mst[rg], v);
            alpha[rg] = __expf(mst[rg] - mn);
            mst[rg] = mn;
        }
#pragma unroll
        for (int nf = 0; nf < 8; ++nf)
#pragma unroll
            for (int rg = 0; rg < 4; ++rg)
                ac[nf][rg] = __expf(ac[nf][rg] - mst[rg]);
#pragma unroll
        for (int rg = 0; rg < 4; ++rg) {
            float sv = 0.0f;
#pragma unroll
            for (int nf = 0; nf < 8; ++nf) sv += ac[nf][rg];
            for (int o = 8; o; o >>= 1) sv += __shfl_xor(sv, o);
            lst[rg] = lst[rg] * alpha[rg] + sv;
        }
#pragma unroll
        for (int nf = 0; nf < 4; ++nf)
#pragma unroll
            for (int rg = 0; rg < 4; ++rg)
                Oacc[nf][rg] *= alpha[rg];

        // ---- P -> scr, PV ----
#pragma unroll
        for (int nf = 0; nf < 8; ++nf)
#pragma unroll
            for (int rg = 0; rg < 4; ++rg) {
                int ldi = lq * 4 + rg;
                scr[ldi * 136 + nf * 16 + l15] = __float2bfloat16(ac[nf][rg]);
            }
#pragma unroll
        for (int ks2 = 0; ks2 < 4; ++ks2) {
            bf16x8 pa = *(const bf16x8*)(&scr[l15 * 136 + ks2 * 32 + lq * 8]);
            bf16x8 vb[4];
#pragma unroll
            for (int nf = 0; nf < 4; ++nf)
                vb[nf] = *(const bf16x8*)(
                    Vb + (nf * 128 + (j0 >> 3) + ks2 * 4 + lq) * 128 + l15 * 8);
            __builtin_amdgcn_s_setprio(1);
#pragma unroll
            for (int nf = 0; nf < 4; ++nf)
                Oacc[nf] = __builtin_amdgcn_mfma_f32_16x16x32_bf16(
                    pa, vb[nf], Oacc[nf], 0, 0, 0);
            __builtin_amdgcn_s_setprio(0);
        }
    }

#pragma unroll
    for (int rg = 0; rg < 4; ++rg) {
        float inv = 1.0f / lst[rg];
#pragma unroll
        for (int nf = 0; nf < 4; ++nf) {
            int row = rowstart + lq * 4 + rg;
            int col = nf * 16 + l15;
            Oa[((long)(b * S + row)) * D + n * 64 + col] =
                __float2bfloat16(Oacc[nf][rg] * inv);
        }
    }
}

// ---------------- single-input LayerNorm (D=1024) ----------------
__global__ __launch_bounds__(256) void ln_single(const float* __restrict__ Zf,
                                                 const float* __restrict__ g,
                                                 const float* __restrict__ beta,
                                                 float* __restrict__ Yf,
                                                 bf16* __restrict__ Yb)
{
    const int D = TD;
    long row = blockIdx.x;
    int tid = threadIdx.x;
    int wave = tid >> 6;

    float v[4], s = 0.0f;
#pragma unroll
    for (int it = 0; it < 4; ++it) {
        int c = tid + it * 256;
        float x = Zf[row * D + c];
        v[it] = x; s += x;
    }
    for (int off = 32; off; off >>= 1) s += __shfl_xor(s, off);
    __shared__ float sm[8];
    if ((tid & 63) == 0) sm[wave] = s;
    __syncthreads();
    float mean = (sm[0] + sm[1] + sm[2] + sm[3]) * (1.0f / D);

    float var = 0.0f;
#pragma unroll
    for (int it = 0; it < 4; ++it) { float d = v[it] - mean; var += d * d; }
    for (int off = 32; off; off >>= 1) var += __shfl_xor(var, off);
    if ((tid & 63) == 0) sm[4 + wave] = var;
    __syncthreads();
    var = (sm[4] + sm[5] + sm[6] + sm[7]) * (1.0f / D);
    float rinv = rsqrtf(var + 1e-5f);

#pragma unroll
    for (int it = 0; it < 4; ++it) {
        int c = tid + it * 256;
        float o = (v[it] - mean) * rinv * g[c] + beta[c];
        if (Yf) Yf[row * D + c] = o;
        if (Yb) Yb[row * D + c] = __float2bfloat16(o);
    }
}

extern "C" void kernel_launch(void* const* d_in, const int* in_sizes, int n_in,
                              void* d_out, int out_size, void* d_ws, size_t ws_size,
                              hipStream_t stream)
{
    const float* w      = (const float*)d_in[0];
    const float* r      = (const float*)d_in[1];
    const float* w_bias = (const float*)d_in[2];
    const float* r_bias = (const float*)d_in[3];
    const float* Wq     = (const float*)d_in[4];
    const float* Wk     = (const float*)d_in[5];
    const float* Wv     = (const float*)d_in[6];
    const float* Wr     = (const float*)d_in[7];
    const float* Wo     = (const float*)d_in[8];
    const float* ln1_g  = (const float*)d_in[9];
    const float* ln1_b  = (const float*)d_in[10];
    const float* W1     = (const float*)d_in[11];
    const float* b1     = (const float*)d_in[12];
    const float* W2     = (const float*)d_in[13];
    const float* b2     = (const float*)d_in[14];
    const float* ln2_g  = (const float*)d_in[15];
    const float* ln2_b  = (const float*)d_in[16];
    float* out = (float*)d_out;

    const int  B = TB, S = TS, D = TD, NH = TNH, DH = TDH, DI = TDI;
    const long MS = (long)B * S;
    const long ND = (long)MS * D;

    char* base = (char*)d_ws;
    size_t off = 0;
    auto alloc = [&](size_t bytes) -> void* {
        void* p = base + off;
        off += (bytes + 255) & ~(size_t)255;
        return p;
    };
    bf16* wqT  = (bf16*)alloc(2UL * D * D);   // wqT..wrT contiguous = fused QKVR B
    bf16* wkT  = (bf16*)alloc(2UL * D * D);
    bf16* wvT  = (bf16*)alloc(2UL * D * D);
    bf16* wrT  = (bf16*)alloc(2UL * D * D);
    bf16* woT  = (bf16*)alloc(2UL * D * D);
    bf16* w1T  = (bf16*)alloc(2UL * D * DI);
    bf16* w2T  = (bf16*)alloc(2UL * DI * D);
    bf16* bufA = (bf16*)alloc(2UL * ND);            // w_bf -> attn_vec
    bf16* bufB = (bf16*)alloc(2UL * ND);            // r_bf -> x_bf
    bf16* Qpk  = (bf16*)alloc(2UL * ND);            // packed Q (fp32 Z overlay later)
    bf16* Kpk  = (bf16*)alloc(2UL * ND);
    bf16* RRpk = (bf16*)alloc(2UL * ND);
    bf16* Vpk  = (bf16*)alloc(2UL * ND);
    bf16* R0   = (bf16*)alloc(2UL * MS * DI);       // h (32 MB)
    size_t need = off;
    (void)in_sizes; (void)n_in; (void)out_size;

    if (ws_size < need) {
        zero_out_k<<<dim3((unsigned)((ND + 255) / 256)), 256, 0, stream>>>(out, ND);
        return;
    }

    bf16* w_bf = bufA;  bf16* attn_vec = bufA;
    bf16* r_bf = bufB;  bf16* x_bf     = bufB;
    bf16* h    = R0;
    float* Pf  = (float*)Qpk;           // 16MB fp32 Z overlays Qpk+Kpk

    // ---- converts + weight transposes ----
    convert2_f2b<<<dim3((unsigned)(ND / (8 * 256)), 2), 256, 0, stream>>>(
        w, r, w_bf, r_bf, ND);
    transpose5_f2b<<<dim3(D / 32, D / 32, 5), 256, 0, stream>>>(
        Wq, Wk, Wv, Wr, Wo, wqT);
    transpose_f2b<<<dim3(DI / 32, D / 32), 256, 0, stream>>>(W1, w1T, D, DI);
    transpose_f2b<<<dim3(D / 32, DI / 32), 256, 0, stream>>>(W2, w2T, DI, D);

    // ---- fused QKV + R projection; Q/K/R/V all written fragment-packed ----
    gemm256_k<1><<<dim3(256, 1), 512, 0, stream>>>(
        w_bf, D, wqT, D, Qpk, Kpk, Vpk, RRpk, w_bias, D, 16, D);

    // ---- fused flash attention (4096 x 1-wave blocks, 16 rows/wave) ----
    flash_attn<<<dim3(4096), 64, 0, stream>>>(Qpk, Kpk, RRpk, Vpk, w_bias, r_bias,
                                              attn_vec);

    // ---- Wo (128^2 tiles, no split-K) + w residual -> Z fp32; LN1 ----
    gemm128_k<3><<<dim3(256, 1), 512, 0, stream>>>(
        attn_vec, D, woT, D, Pf, w, nullptr, nullptr, D, 32, D);
    ln_single<<<dim3((unsigned)MS), 256, 0, stream>>>(Pf, ln1_g, ln1_b, nullptr, x_bf);

    // ---- FFN1: bias+relu -> h ----
    gemm256_k<2><<<dim3(256, 1), 512, 0, stream>>>(
        x_bf, D, w1T, D, h, nullptr, nullptr, nullptr, b1, D, 16, DI);

    // ---- FFN2 (128^2 tiles, K=4096) + b2 + x residual -> Z fp32; LN2 ----
    gemm128_k<4><<<dim3(256, 1), 512, 0, stream>>>(
        h, DI, w2T, DI, Pf, nullptr, x_bf, b2, DI, 32, D);
    ln_single<<<dim3((unsigned)MS), 256, 0, stream>>>(Pf, ln2_g, ln2_b, out, nullptr);
}

// Round 5
// 369.551 us; speedup vs baseline: 1.0029x; 1.0029x over previous
//
#include <hip/hip_runtime.h>
#include <hip/hip_bf16.h>

using bf16 = __hip_bfloat16;
typedef __attribute__((ext_vector_type(8))) short bf16x8;
typedef __attribute__((ext_vector_type(4))) short bf16x4;
typedef __attribute__((ext_vector_type(4))) float f32x4;

static constexpr int TB  = 4;
static constexpr int TS  = 1024;
static constexpr int TD  = 1024;
static constexpr int TNH = 16;
static constexpr int TDH = 64;
static constexpr int TDI = 4096;

__device__ __forceinline__ void gll16(const bf16* g, bf16* l)
{
    __builtin_amdgcn_global_load_lds(
        (const __attribute__((address_space(1))) void*)g,
        (__attribute__((address_space(3))) void*)l, 16, 0, 0);
}

// ---------------- fallback ----------------
__global__ __launch_bounds__(256) void zero_out_k(float* __restrict__ out, long n)
{
    long i = (long)blockIdx.x * 256 + threadIdx.x;
    if (i < n) out[i] = 0.0f;
}

// ---------------- fp32 -> bf16, 8/thread, two tensors ----------------
__global__ __launch_bounds__(256) void convert2_f2b(const float* __restrict__ a,
                                                    const float* __restrict__ b,
                                                    bf16* __restrict__ oa,
                                                    bf16* __restrict__ ob, long n)
{
    const float* src = blockIdx.y ? b : a;
    bf16* dst = blockIdx.y ? ob : oa;
    long i = ((long)blockIdx.x * 256 + threadIdx.x) * 8;
    if (i >= n) return;
    float4 f0 = *(const float4*)(src + i);
    float4 f1 = *(const float4*)(src + i + 4);
    bf16 t[8] = {__float2bfloat16(f0.x), __float2bfloat16(f0.y),
                 __float2bfloat16(f0.z), __float2bfloat16(f0.w),
                 __float2bfloat16(f1.x), __float2bfloat16(f1.y),
                 __float2bfloat16(f1.z), __float2bfloat16(f1.w)};
    *(bf16x8*)(dst + i) = *(bf16x8*)t;
}

// ---------------- transpose fp32 [R,C] -> bf16 [C,R] ----------------
__global__ __launch_bounds__(256) void transpose_f2b(const float* __restrict__ in,
                                                     bf16* __restrict__ out,
                                                     int R, int C)
{
    __shared__ float tile[32][33];
    int c0 = blockIdx.x * 32, r0 = blockIdx.y * 32;
    int tx = threadIdx.x & 31, ty = threadIdx.x >> 5;
#pragma unroll
    for (int dy = 0; dy < 32; dy += 8)
        tile[ty + dy][tx] = in[(long)(r0 + ty + dy) * C + (c0 + tx)];
    __syncthreads();
#pragma unroll
    for (int dy = 0; dy < 32; dy += 8)
        out[(long)(c0 + ty + dy) * R + (r0 + tx)] = __float2bfloat16(tile[tx][ty + dy]);
}

// ---------------- 5x square D x D transpose ----------------
__global__ __launch_bounds__(256) void transpose5_f2b(const float* __restrict__ p0,
                                                      const float* __restrict__ p1,
                                                      const float* __restrict__ p2,
                                                      const float* __restrict__ p3,
                                                      const float* __restrict__ p4,
                                                      bf16* __restrict__ dstBase)
{
    __shared__ float tile[32][33];
    const int D = TD;
    int z = blockIdx.z;
    const float* in = (z == 0) ? p0 : (z == 1) ? p1 : (z == 2) ? p2 : (z == 3) ? p3 : p4;
    bf16* out = dstBase + (long)z * D * D;
    int c0 = blockIdx.x * 32, r0 = blockIdx.y * 32;
    int tx = threadIdx.x & 31, ty = threadIdx.x >> 5;
#pragma unroll
    for (int dy = 0; dy < 32; dy += 8)
        tile[ty + dy][tx] = in[(long)(r0 + ty + dy) * D + (c0 + tx)];
    __syncthreads();
#pragma unroll
    for (int dy = 0; dy < 32; dy += 8)
        out[(long)(c0 + ty + dy) * D + (r0 + tx)] = __float2bfloat16(tile[tx][ty + dy]);
}

// ======================================================================
// 256x256 x BK=64, 8-wave (2Mx4N), 8-phase pipelined GEMM (T1..T5)
// MODE 1: fused QKV+R, fragment-packed writes for Q/K/R AND V.
// MODE 2: bias+relu bf16.
// Supertile mapping: each XCD owns 4x4-tile rectangles.
// ======================================================================

__device__ __forceinline__ void stage_half(const bf16* __restrict__ X, long ldx,
                                           long rbase, long kcol,
                                           bf16* lds, int srow)
{
    gll16(X + (rbase + srow) * ldx + kcol, lds);
    gll16(X + (rbase + 128 + srow) * ldx + kcol, lds + 4096);
}

template<int MODE>
__global__ __launch_bounds__(512, 2) void gemm256_k(
    const bf16* __restrict__ A, long lda,
    const bf16* __restrict__ Bt, long ldb,
    bf16* __restrict__ O0, bf16* __restrict__ O1,
    bf16* __restrict__ O2, bf16* __restrict__ O3,
    const float* __restrict__ bias,
    int K, int GY, long ldc)
{
    __shared__ bf16 LDSbf[65536];   // 128 KiB

    const int NT = K >> 6;
    const int NI = NT >> 1;

    // bijective XCD swizzle: each XCD = contiguous wgid chunk of 32
    const int nwg = gridDim.x;
    const int orig = blockIdx.x;
    const int q = nwg >> 3, r = nwg & 7;
    const int xcd = orig & 7, idx = orig >> 3;
    const int wgid = (xcd < r ? xcd * (q + 1) : r * (q + 1) + (xcd - r) * q) + idx;

    // supertile mapping: 16 supertiles of 4x4 tiles
    int tx, ty;
    {
        const int l = wgid & 15;
        const int st = wgid >> 4;
        const int lty = l & 3, ltx = l >> 2;
        if (MODE == 1) {
            if (st < 12) { ty = (st & 3) * 4 + lty; tx = (st >> 2) * 4 + ltx; }
            else { int s2 = st - 12; ty = 16 + s2 * 4 + lty; tx = 12 + ltx; }
        } else {
            ty = (st & 3) * 4 + lty; tx = (st >> 2) * 4 + ltx;
        }
    }
    const long row0 = (long)ty * 256;
    const int col0 = tx * 256;

    const int tid = threadIdx.x;
    const int lane = tid & 63;
    const int wave = tid >> 6;       // 0..7
    const int wm2 = wave >> 2;       // 0..1  (M half)
    const int wn4 = wave & 3;        // 0..3  (N quarter)
    const int l15 = lane & 15;
    const int lq  = lane >> 4;       // 0..3

    const int slot = ((l15 & 1) << 2) | (lq ^ ((l15 >> 1) & 3));
    const int rdA = (wm2 * 64 + (l15 >> 1)) * 64 + slot * 8;
    const int rdB = 16384 + (wn4 * 32 + (l15 >> 1)) * 64 + slot * 8;

    const int srow  = wave * 16 + ((lane >> 3) << 1) + ((lane >> 2) & 1);
    const int scol8 = ((lane & 3) ^ ((lane >> 3) & 3)) * 8;

    f32x4 acc[8][4] = {};
    bf16x8 af[8], bb[4];

#define SA(t, db, kh) stage_half(A, lda, row0, (long)(t) * 64 + (kh) * 32 + scol8, \
                                 LDSbf + (db) * 32768 + (kh) * 8192 + wave * 512, srow)
#define SB(t, db, kh) stage_half(Bt, ldb, (long)col0, (long)(t) * 64 + (kh) * 32 + scol8, \
                                 LDSbf + (db) * 32768 + 16384 + (kh) * 8192 + wave * 512, srow)
#define RD_A(bp, kh) do {                                                              \
    _Pragma("unroll")                                                                  \
    for (int i_ = 0; i_ < 8; ++i_)                                                     \
        af[i_] = *(const bf16x8*)(LDSbf + (bp) * 32768 + (kh) * 8192 + rdA + i_ * 512);\
    } while (0)
#define RD_B(bp, kh, jh) do {                                                          \
    bb[(jh)*2]   = *(const bf16x8*)(LDSbf + (bp)*32768 + (kh)*8192 + rdB + ((jh)*2)*512);   \
    bb[(jh)*2+1] = *(const bf16x8*)(LDSbf + (bp)*32768 + (kh)*8192 + rdB + ((jh)*2+1)*512); \
    } while (0)
#define MM(jh) do {                                                                    \
    __builtin_amdgcn_s_setprio(1);                                                     \
    _Pragma("unroll")                                                                  \
    for (int i_ = 0; i_ < 8; ++i_) {                                                   \
        acc[i_][(jh)*2]   = __builtin_amdgcn_mfma_f32_16x16x32_bf16(af[i_], bb[(jh)*2],   acc[i_][(jh)*2],   0, 0, 0); \
        acc[i_][(jh)*2+1] = __builtin_amdgcn_mfma_f32_16x16x32_bf16(af[i_], bb[(jh)*2+1], acc[i_][(jh)*2+1], 0, 0, 0); \
    }                                                                                  \
    __builtin_amdgcn_s_setprio(0);                                                     \
    } while (0)
#define BAR       __builtin_amdgcn_s_barrier()
#define WLGKM0    do { asm volatile("s_waitcnt lgkmcnt(0)" ::: "memory");              \
                       __builtin_amdgcn_sched_barrier(0); } while (0)
#define WVM6      asm volatile("s_waitcnt vmcnt(6)" ::: "memory")

    SA(0, 0, 0); SB(0, 0, 0); SA(0, 0, 1); SB(0, 0, 1); SA(1, 1, 0);
    WVM6; BAR;

    for (int it = 0; it < NI; ++it) {
        const int T  = 2 * it;
        const int t1 = T + 1;
        const int t2 = (T + 2 < NT) ? T + 2 : NT - 1;
        const int t3 = (T + 3 < NT) ? T + 3 : NT - 1;

        RD_A(0, 0); RD_B(0, 0, 0); SB(t1, 1, 0);
        BAR; WLGKM0; MM(0); BAR;
        RD_B(0, 0, 1); SA(t1, 1, 1);
        BAR; WLGKM0; MM(1); WVM6; BAR;
        RD_A(0, 1); RD_B(0, 1, 0); SB(t1, 1, 1);
        BAR; WLGKM0; MM(0); BAR;
        RD_B(0, 1, 1); SA(t2, 0, 0);
        BAR; WLGKM0; MM(1); WVM6; BAR;
        RD_A(1, 0); RD_B(1, 0, 0); SB(t2, 0, 0);
        BAR; WLGKM0; MM(0); BAR;
        RD_B(1, 0, 1); SA(t2, 0, 1);
        BAR; WLGKM0; MM(1); WVM6; BAR;
        RD_A(1, 1); RD_B(1, 1, 0); SB(t2, 0, 1);
        BAR; WLGKM0; MM(0); BAR;
        RD_B(1, 1, 1); SA(t3, 1, 0);
        BAR; WLGKM0; MM(1); WVM6; BAR;
    }
    asm volatile("s_waitcnt vmcnt(0)" ::: "memory");

#undef SA
#undef SB
#undef RD_A
#undef RD_B
#undef MM
#undef BAR
#undef WLGKM0
#undef WVM6

    // ---- epilogue ----
    if (MODE == 1) {
        const int sel = tx >> 2;                       // 0=Q 1=K 2=V 3=R
        bf16* O = (sel == 0) ? O0 : (sel == 1) ? O1 : (sel == 2) ? O2 : O3;
        const int coladj = sel << 10;
        const long rowadj = (sel == 3) ? 4096 : 0;
#pragma unroll
        for (int i = 0; i < 8; ++i) {
            long mrow0 = row0 - rowadj + wm2 * 128 + i * 16 + lq * 4;
#pragma unroll
            for (int j = 0; j < 4; ++j) {
                int nc = col0 - coladj + wn4 * 64 + j * 16 + l15;
                if (sel == 2) {
                    // V packed: 4 consecutive s -> one 8B store
                    long b_ = mrow0 >> 10;
                    int s  = (int)mrow0 & 1023;
                    int n_ = nc >> 6, d = nc & 63;
                    long pidx = ((b_ * 16 + n_) << 16)
                              + ((d >> 4) * 128 + (s >> 3)) * 128
                              + (d & 15) * 8 + (s & 7);
                    bf16 t4[4];
#pragma unroll
                    for (int rg = 0; rg < 4; ++rg)
                        t4[rg] = __float2bfloat16(acc[i][j][rg]);
                    *(bf16x4*)(O + pidx) = *(bf16x4*)t4;
                } else {
#pragma unroll
                    for (int rg = 0; rg < 4; ++rg) {
                        float v = acc[i][j][rg];
                        if (sel == 0) v += bias[nc];
                        long mrow = mrow0 + rg;
                        long b_ = mrow >> 10;
                        int s  = (int)mrow & 1023;
                        int n_ = nc >> 6, d = nc & 63;
                        long pidx = ((b_ * 16 + n_) << 16)
                                  + ((s >> 4) * 8 + (d >> 3)) * 128
                                  + (s & 15) * 8 + (d & 7);
                        O[pidx] = __float2bfloat16(v);
                    }
                }
            }
        }
    } else {
#pragma unroll
        for (int i = 0; i < 8; ++i) {
            long rb = (row0 + wm2 * 128 + i * 16 + lq * 4) * ldc;
#pragma unroll
            for (int j = 0; j < 4; ++j) {
                int nc = col0 + wn4 * 64 + j * 16 + l15;
#pragma unroll
                for (int rg = 0; rg < 4; ++rg) {
                    float v = acc[i][j][rg] + bias[nc];
                    v = fmaxf(v, 0.0f);
                    O0[rb + (long)rg * ldc + nc] = __float2bfloat16(v);
                }
            }
        }
    }
}

// ======================================================================
// 128x128 x BK=64, 8-wave (2Mx4N), 4-phase pipelined GEMM, no split-K.
// LDS 64KB -> 2 blocks/CU. Supertile mapping 8x4 per XCD.
// MODE 3: z = acc + residf(fp32)           -> Zf fp32   (Wo + w residual)
// MODE 4: z = acc + bias + residb(bf16)    -> Zf fp32   (FFN2 + b2 + x)
// ======================================================================
template<int MODE>
__global__ __launch_bounds__(512, 2) void gemm128_k(
    const bf16* __restrict__ A, long lda,
    const bf16* __restrict__ Bt, long ldb,
    float* __restrict__ Zf,
    const float* __restrict__ residf, const bf16* __restrict__ residb,
    const float* __restrict__ bias,
    int K, int GY, long ldc)
{
    __shared__ bf16 LDSbf[32768];   // 64 KiB

    const int NT = K >> 6;
    const int NI = NT >> 1;

    const int nwg = gridDim.x;
    const int orig = blockIdx.x;
    const int q = nwg >> 3, r = nwg & 7;
    const int xcd = orig & 7, idx = orig >> 3;
    const int wgid = (xcd < r ? xcd * (q + 1) : r * (q + 1) + (xcd - r) * q) + idx;

    // supertile: 8 supertiles of 8ty x 4tx (grid 32x8)
    const int l = wgid & 31;
    const int sup = wgid >> 5;
    const int ty = (sup & 3) * 8 + (l & 7);
    const int tx = (sup >> 2) * 4 + (l >> 3);
    const long row0 = (long)ty * 128;
    const long col0 = (long)tx * 128;

    const int tid = threadIdx.x;
    const int lane = tid & 63;
    const int wave = tid >> 6;
    const int wm2 = wave >> 2;       // 0..1: 64-row half
    const int wn4 = wave & 3;        // 0..3: 32-col quarter
    const int l15 = lane & 15;
    const int lq  = lane >> 4;

    const int slot = ((l15 & 1) << 2) | (lq ^ ((l15 >> 1) & 3));
    const int rdA = (wm2 * 32 + (l15 >> 1)) * 64 + slot * 8;
    const int rdB = 8192 + (wn4 * 16 + (l15 >> 1)) * 64 + slot * 8;

    const int srow  = (tid >> 3) * 2 + ((tid >> 2) & 1);          // 0..127
    const int scol8 = ((tid & 3) ^ ((tid >> 3) & 3)) * 8;

    f32x4 acc[4][2] = {};
    bf16x8 af[4], bb[2];

#define SA(t, db, kh) gll16(A + (row0 + srow) * lda + (long)(t) * 64 + (kh) * 32 + scol8, \
                            LDSbf + (db) * 16384 + (kh) * 4096 + wave * 512)
#define SB(t, db, kh) gll16(Bt + (col0 + srow) * ldb + (long)(t) * 64 + (kh) * 32 + scol8, \
                            LDSbf + (db) * 16384 + 8192 + (kh) * 4096 + wave * 512)
#define RD(db, kh) do {                                                                \
    _Pragma("unroll")                                                                  \
    for (int i_ = 0; i_ < 4; ++i_)                                                     \
        af[i_] = *(const bf16x8*)(LDSbf + (db) * 16384 + (kh) * 4096 + rdA + i_ * 512);\
    _Pragma("unroll")                                                                  \
    for (int j_ = 0; j_ < 2; ++j_)                                                     \
        bb[j_] = *(const bf16x8*)(LDSbf + (db) * 16384 + (kh) * 4096 + rdB + j_ * 512);\
    } while (0)
#define MM8 do {                                                                       \
    __builtin_amdgcn_s_setprio(1);                                                     \
    _Pragma("unroll")                                                                  \
    for (int i_ = 0; i_ < 4; ++i_) {                                                   \
        acc[i_][0] = __builtin_amdgcn_mfma_f32_16x16x32_bf16(af[i_], bb[0], acc[i_][0], 0, 0, 0); \
        acc[i_][1] = __builtin_amdgcn_mfma_f32_16x16x32_bf16(af[i_], bb[1], acc[i_][1], 0, 0, 0); \
    }                                                                                  \
    __builtin_amdgcn_s_setprio(0);                                                     \
    } while (0)
#define BAR       __builtin_amdgcn_s_barrier()
#define WLGKM0    do { asm volatile("s_waitcnt lgkmcnt(0)" ::: "memory");              \
                       __builtin_amdgcn_sched_barrier(0); } while (0)
#define WVM4      asm volatile("s_waitcnt vmcnt(4)" ::: "memory")

    SA(0, 0, 0); SB(0, 0, 0); SA(0, 0, 1); SB(0, 0, 1); SA(1, 1, 0); SB(1, 1, 0);
    WVM4; BAR;

    for (int it = 0; it < NI; ++it) {
        const int T  = 2 * it;
        const int t1 = T + 1;
        const int t2 = (T + 2 < NT) ? T + 2 : NT - 1;
        const int t3 = (T + 3 < NT) ? T + 3 : NT - 1;

        RD(0, 0); SA(t1, 1, 1); SB(t1, 1, 1);
        BAR; WLGKM0; MM8; WVM4; BAR;
        RD(0, 1); SA(t2, 0, 0); SB(t2, 0, 0);
        BAR; WLGKM0; MM8; WVM4; BAR;
        RD(1, 0); SA(t2, 0, 1); SB(t2, 0, 1);
        BAR; WLGKM0; MM8; WVM4; BAR;
        RD(1, 1); SA(t3, 1, 0); SB(t3, 1, 0);
        BAR; WLGKM0; MM8; WVM4; BAR;
    }
    asm volatile("s_waitcnt vmcnt(0)" ::: "memory");

#undef SA
#undef SB
#undef RD
#undef MM8
#undef BAR
#undef WLGKM0
#undef WVM4

    // ---- fused epilogue -> fp32 Z ----
#pragma unroll
    for (int i = 0; i < 4; ++i) {
        long mrow0 = row0 + wm2 * 64 + i * 16 + lq * 4;
#pragma unroll
        for (int j = 0; j < 2; ++j) {
            int nc = (int)col0 + wn4 * 32 + j * 16 + l15;
#pragma unroll
            for (int rg = 0; rg < 4; ++rg) {
                long ridx = (mrow0 + rg) * ldc + nc;
                float v = acc[i][j][rg];
                if (MODE == 3) v += residf[ridx];
                else           v += bias[nc] + __bfloat162float(residb[ridx]);
                Zf[ridx] = v;
            }
        }
    }
}

// ======================================================================
// fused flash attention with Transformer-XL rel-shift — single-wave
// blocks, 16 q-rows per wave, fragment-packed direct global loads.
// grid = 4096 x 64 threads. LDS 5.3KB/block.
// launch_bounds(64,2): let RA use ~100-128 regs (R4's (64,4) squeezed to
// 64 -> 34MB spill traffic). No setprio (R4: regressed 16us, m190-like).
// scr strides 165 (bd, diag-read conflict-free) / 140 (P, 8->4-way).
// ======================================================================
__global__ __launch_bounds__(64, 2) void flash_attn(
    const bf16* __restrict__ Qpk, const bf16* __restrict__ Kpk,
    const bf16* __restrict__ RRpk, const bf16* __restrict__ Vpk,
    const float* __restrict__ wbias, const float* __restrict__ rbias,
    bf16* __restrict__ Oa)
{
    const int S = TS, D = TD;
    __shared__ bf16 scr[16 * 165];   // 5280 B

    const int orig = blockIdx.x;               // 0..4095
    const int xcd = orig & 7, idx = orig >> 3; // idx 0..511
    const int bn = xcd * 8 + (idx & 7);        // 8 bn per XCD
    const int rem = idx >> 3;                  // 0..63
    const int r16 = 63 - rem;                  // heavy row-groups first
    const int it = r16 >> 3;
    const int rowstart = r16 * 16;
    const int dwq = (r16 & 7) * 16;
    const int b = bn >> 4, n = bn & 15;

    const int lane = threadIdx.x;
    const int l15 = lane & 15, lq = lane >> 4;

    const bf16* Qb = Qpk  + (long)bn * 65536;
    const bf16* Kb = Kpk  + (long)bn * 65536;
    const bf16* Rb = RRpk + (long)bn * 65536;
    const bf16* Vb = Vpk  + (long)bn * 65536;

    bf16x8 afw[2], afr[2];
#pragma unroll
    for (int ks = 0; ks < 2; ++ks) {
        afw[ks] = *(const bf16x8*)(Qb + (r16 * 8 + ks * 4 + lq) * 128 + l15 * 8);
        bf16 tmp[8];
#pragma unroll
        for (int jj = 0; jj < 8; ++jj) {
            int di_ = n * 64 + ks * 32 + lq * 8 + jj;
            float f = __bfloat162float(((const bf16*)&afw[ks])[jj])
                      + rbias[di_] - wbias[di_];
            tmp[jj] = __float2bfloat16(f);
        }
        afr[ks] = *(bf16x8*)tmp;
    }

    float mst[4], lst[4];
    f32x4 Oacc[4] = {};
#pragma unroll
    for (int rg = 0; rg < 4; ++rg) { mst[rg] = -1e30f; lst[rg] = 0.0f; }

    const int cofs16 = 1008 - rowstart;

    for (int jt = 0; jt <= it; ++jt) {
        const int j0 = jt * 128;
        const int rbt = (j0 + cofs16) >> 4;

        // ---- bd = (q + r_bias) . RR : 9 frags (144 cols), groups 5+4 ----
#pragma unroll
        for (int g = 0; g < 2; ++g) {
            const int NF = g ? 4 : 5;
            f32x4 bdl[5] = {};
#pragma unroll
            for (int ks = 0; ks < 2; ++ks) {
                bf16x8 bfr[5];
#pragma unroll
                for (int f = 0; f < 5; ++f) {
                    if (f < NF) {
                        int t = rbt + g * 5 + f;
                        if (t > 63) t = 63;   // clamped rows land only in masked cols
                        bfr[f] = *(const bf16x8*)(Rb + (t * 8 + ks * 4 + lq) * 128 + l15 * 8);
                    }
                }
#pragma unroll
                for (int f = 0; f < 5; ++f)
                    if (f < NF)
                        bdl[f] = __builtin_amdgcn_mfma_f32_16x16x32_bf16(
                            afr[ks], bfr[f], bdl[f], 0, 0, 0);
            }
#pragma unroll
            for (int f = 0; f < 5; ++f)
                if (f < NF)
#pragma unroll
                    for (int rg = 0; rg < 4; ++rg) {
                        int ldi = lq * 4 + rg;
                        scr[ldi * 165 + (g * 5 + f) * 16 + l15] =
                            __float2bfloat16(bdl[f][rg]);
                    }
        }

        // ---- ac = (q + w_bias) . K  (K frags in 2 groups of 4: VGPR cap) ----
        f32x4 ac[8] = {};
#pragma unroll
        for (int ks = 0; ks < 2; ++ks) {
#pragma unroll
            for (int h = 0; h < 2; ++h) {
                bf16x8 bk[4];
#pragma unroll
                for (int f = 0; f < 4; ++f)
                    bk[f] = *(const bf16x8*)(
                        Kb + (((j0 >> 4) + h * 4 + f) * 8 + ks * 4 + lq) * 128 + l15 * 8);
#pragma unroll
                for (int f = 0; f < 4; ++f)
                    ac[h * 4 + f] = __builtin_amdgcn_mfma_f32_16x16x32_bf16(
                        afw[ks], bk[f], ac[h * 4 + f], 0, 0, 0);
            }
        }

        // ---- rel-shift add + scale + causal mask ----
        const bool diag = (jt == it);
#pragma unroll
        for (int nf = 0; nf < 8; ++nf)
#pragma unroll
            for (int rg = 0; rg < 4; ++rg) {
                int ldi = lq * 4 + rg;
                int col = nf * 16 + l15;
                float bdv = __bfloat162float(scr[ldi * 165 + (col + 15 - ldi)]);
                float s = (ac[nf][rg] + bdv) * 0.125f;
                if (diag && (col > dwq + ldi)) s = -1e30f;
                ac[nf][rg] = s;
            }

        // ---- online softmax ----
        float alpha[4];
#pragma unroll
        for (int rg = 0; rg < 4; ++rg) {
            float v = -1e30f;
#pragma unroll
            for (int nf = 0; nf < 8; ++nf) v = fmaxf(v, ac[nf][rg]);
            for (int o = 8; o; o >>= 1) v = fmaxf(v, __shfl_xor(v, o));
            float mn = fmaxf(mst[rg], v);
            alpha[rg] = __expf(mst[rg] - mn);
            mst[rg] = mn;
        }
#pragma unroll
        for (int nf = 0; nf < 8; ++nf)
#pragma unroll
            for (int rg = 0; rg < 4; ++rg)
                ac[nf][rg] = __expf(ac[nf][rg] - mst[rg]);
#pragma unroll
        for (int rg = 0; rg < 4; ++rg) {
            float sv = 0.0f;
#pragma unroll
            for (int nf = 0; nf < 8; ++nf) sv += ac[nf][rg];
            for (int o = 8; o; o >>= 1) sv += __shfl_xor(sv, o);
            lst[rg] = lst[rg] * alpha[rg] + sv;
        }
#pragma unroll
        for (int nf = 0; nf < 4; ++nf)
#pragma unroll
            for (int rg = 0; rg < 4; ++rg)
                Oacc[nf][rg] *= alpha[rg];

        // ---- P -> scr, PV ----
#pragma unroll
        for (int nf = 0; nf < 8; ++nf)
#pragma unroll
            for (int rg = 0; rg < 4; ++rg) {
                int ldi = lq * 4 + rg;
                scr[ldi * 140 + nf * 16 + l15] = __float2bfloat16(ac[nf][rg]);
            }
#pragma unroll
        for (int ks2 = 0; ks2 < 4; ++ks2) {
            bf16x8 pa = *(const bf16x8*)(&scr[l15 * 140 + ks2 * 32 + lq * 8]);
            bf16x8 vb[4];
#pragma unroll
            for (int nf = 0; nf < 4; ++nf)
                vb[nf] = *(const bf16x8*)(
                    Vb + (nf * 128 + (j0 >> 3) + ks2 * 4 + lq) * 128 + l15 * 8);
#pragma unroll
            for (int nf = 0; nf < 4; ++nf)
                Oacc[nf] = __builtin_amdgcn_mfma_f32_16x16x32_bf16(
                    pa, vb[nf], Oacc[nf], 0, 0, 0);
        }
    }

#pragma unroll
    for (int rg = 0; rg < 4; ++rg) {
        float inv = 1.0f / lst[rg];
#pragma unroll
        for (int nf = 0; nf < 4; ++nf) {
            int row = rowstart + lq * 4 + rg;
            int col = nf * 16 + l15;
            Oa[((long)(b * S + row)) * D + n * 64 + col] =
                __float2bfloat16(Oacc[nf][rg] * inv);
        }
    }
}

// ---------------- single-input LayerNorm (D=1024) ----------------
__global__ __launch_bounds__(256) void ln_single(const float* __restrict__ Zf,
                                                 const float* __restrict__ g,
                                                 const float* __restrict__ beta,
                                                 float* __restrict__ Yf,
                                                 bf16* __restrict__ Yb)
{
    const int D = TD;
    long row = blockIdx.x;
    int tid = threadIdx.x;
    int wave = tid >> 6;

    float v[4], s = 0.0f;
#pragma unroll
    for (int it = 0; it < 4; ++it) {
        int c = tid + it * 256;
        float x = Zf[row * D + c];
        v[it] = x; s += x;
    }
    for (int off = 32; off; off >>= 1) s += __shfl_xor(s, off);
    __shared__ float sm[8];
    if ((tid & 63) == 0) sm[wave] = s;
    __syncthreads();
    float mean = (sm[0] + sm[1] + sm[2] + sm[3]) * (1.0f / D);

    float var = 0.0f;
#pragma unroll
    for (int it = 0; it < 4; ++it) { float d = v[it] - mean; var += d * d; }
    for (int off = 32; off; off >>= 1) var += __shfl_xor(var, off);
    if ((tid & 63) == 0) sm[4 + wave] = var;
    __syncthreads();
    var = (sm[4] + sm[5] + sm[6] + sm[7]) * (1.0f / D);
    float rinv = rsqrtf(var + 1e-5f);

#pragma unroll
    for (int it = 0; it < 4; ++it) {
        int c = tid + it * 256;
        float o = (v[it] - mean) * rinv * g[c] + beta[c];
        if (Yf) Yf[row * D + c] = o;
        if (Yb) Yb[row * D + c] = __float2bfloat16(o);
    }
}

extern "C" void kernel_launch(void* const* d_in, const int* in_sizes, int n_in,
                              void* d_out, int out_size, void* d_ws, size_t ws_size,
                              hipStream_t stream)
{
    const float* w      = (const float*)d_in[0];
    const float* r      = (const float*)d_in[1];
    const float* w_bias = (const float*)d_in[2];
    const float* r_bias = (const float*)d_in[3];
    const float* Wq     = (const float*)d_in[4];
    const float* Wk     = (const float*)d_in[5];
    const float* Wv     = (const float*)d_in[6];
    const float* Wr     = (const float*)d_in[7];
    const float* Wo     = (const float*)d_in[8];
    const float* ln1_g  = (const float*)d_in[9];
    const float* ln1_b  = (const float*)d_in[10];
    const float* W1     = (const float*)d_in[11];
    const float* b1     = (const float*)d_in[12];
    const float* W2     = (const float*)d_in[13];
    const float* b2     = (const float*)d_in[14];
    const float* ln2_g  = (const float*)d_in[15];
    const float* ln2_b  = (const float*)d_in[16];
    float* out = (float*)d_out;

    const int  B = TB, S = TS, D = TD, NH = TNH, DH = TDH, DI = TDI;
    const long MS = (long)B * S;
    const long ND = (long)MS * D;

    char* base = (char*)d_ws;
    size_t off = 0;
    auto alloc = [&](size_t bytes) -> void* {
        void* p = base + off;
        off += (bytes + 255) & ~(size_t)255;
        return p;
    };
    bf16* wqT  = (bf16*)alloc(2UL * D * D);   // wqT..wrT contiguous = fused QKVR B
    bf16* wkT  = (bf16*)alloc(2UL * D * D);
    bf16* wvT  = (bf16*)alloc(2UL * D * D);
    bf16* wrT  = (bf16*)alloc(2UL * D * D);
    bf16* woT  = (bf16*)alloc(2UL * D * D);
    bf16* w1T  = (bf16*)alloc(2UL * D * DI);
    bf16* w2T  = (bf16*)alloc(2UL * DI * D);
    bf16* bufA = (bf16*)alloc(2UL * ND);            // w_bf -> attn_vec
    bf16* bufB = (bf16*)alloc(2UL * ND);            // r_bf -> x_bf
    bf16* Qpk  = (bf16*)alloc(2UL * ND);            // packed Q (fp32 Z overlay later)
    bf16* Kpk  = (bf16*)alloc(2UL * ND);
    bf16* RRpk = (bf16*)alloc(2UL * ND);
    bf16* Vpk  = (bf16*)alloc(2UL * ND);
    bf16* R0   = (bf16*)alloc(2UL * MS * DI);       // h (32 MB)
    size_t need = off;
    (void)in_sizes; (void)n_in; (void)out_size;

    if (ws_size < need) {
        zero_out_k<<<dim3((unsigned)((ND + 255) / 256)), 256, 0, stream>>>(out, ND);
        return;
    }

    bf16* w_bf = bufA;  bf16* attn_vec = bufA;
    bf16* r_bf = bufB;  bf16* x_bf     = bufB;
    bf16* h    = R0;
    float* Pf  = (float*)Qpk;           // 16MB fp32 Z overlays Qpk+Kpk

    // ---- converts + weight transposes ----
    convert2_f2b<<<dim3((unsigned)(ND / (8 * 256)), 2), 256, 0, stream>>>(
        w, r, w_bf, r_bf, ND);
    transpose5_f2b<<<dim3(D / 32, D / 32, 5), 256, 0, stream>>>(
        Wq, Wk, Wv, Wr, Wo, wqT);
    transpose_f2b<<<dim3(DI / 32, D / 32), 256, 0, stream>>>(W1, w1T, D, DI);
    transpose_f2b<<<dim3(D / 32, DI / 32), 256, 0, stream>>>(W2, w2T, DI, D);

    // ---- fused QKV + R projection; Q/K/R/V all written fragment-packed ----
    gemm256_k<1><<<dim3(256, 1), 512, 0, stream>>>(
        w_bf, D, wqT, D, Qpk, Kpk, Vpk, RRpk, w_bias, D, 16, D);

    // ---- fused flash attention (4096 x 1-wave blocks, 16 rows/wave) ----
    flash_attn<<<dim3(4096), 64, 0, stream>>>(Qpk, Kpk, RRpk, Vpk, w_bias, r_bias,
                                              attn_vec);

    // ---- Wo (128^2 tiles, no split-K) + w residual -> Z fp32; LN1 ----
    gemm128_k<3><<<dim3(256, 1), 512, 0, stream>>>(
        attn_vec, D, woT, D, Pf, w, nullptr, nullptr, D, 32, D);
    ln_single<<<dim3((unsigned)MS), 256, 0, stream>>>(Pf, ln1_g, ln1_b, nullptr, x_bf);

    // ---- FFN1: bias+relu -> h ----
    gemm256_k<2><<<dim3(256, 1), 512, 0, stream>>>(
        x_bf, D, w1T, D, h, nullptr, nullptr, nullptr, b1, D, 16, DI);

    // ---- FFN2 (128^2 tiles, K=4096) + b2 + x residual -> Z fp32; LN2 ----
    gemm128_k<4><<<dim3(256, 1), 512, 0, stream>>>(
        h, DI, w2T, DI, Pf, nullptr, x_bf, b2, DI, 32, D);
    ln_single<<<dim3((unsigned)MS), 256, 0, stream>>>(Pf, ln2_g, ln2_b, out, nullptr);
}